// Round 2
// baseline (312.529 us; speedup 1.0000x reference)
//
#include <hip/hip_runtime.h>
#include <hip/hip_bf16.h>

#define NN   1024
#define HD   64
#define MSGD 64
#define HIDD 128

typedef __attribute__((ext_vector_type(4))) float f4;
typedef __attribute__((ext_vector_type(2))) float f2;
typedef __attribute__((ext_vector_type(8))) __bf16 bf16x8;
typedef __attribute__((ext_vector_type(16))) float f32x16;
typedef __attribute__((ext_vector_type(4))) unsigned int u32x4;
typedef unsigned short ushort_t;

__device__ __forceinline__ float silu_f(float v) {
    float e = __expf(-v);
    return v * __builtin_amdgcn_rcpf(1.0f + e);
}

__device__ __forceinline__ ushort_t to_bf16_bits(float v) {
    return __builtin_bit_cast(ushort_t, (__bf16)v);
}

__device__ __forceinline__ unsigned pack2(float a, float b) {
    return (unsigned)to_bf16_bits(a) | ((unsigned)to_bf16_bits(b) << 16);
}

#define ZERO16 {0.f,0.f,0.f,0.f,0.f,0.f,0.f,0.f,0.f,0.f,0.f,0.f,0.f,0.f,0.f,0.f}

// ---------------------------------------------------------------------------
// Kernel A: Ah = h@ew1[0:64] + eb1, Bh = h@ew1[64:128]; pack ew2^T / cw1^T
// into 32x32x16 MFMA A-fragment order (bf16).
// A-frag (32x32x16): lane l holds A[m = l&31][k = (l>>5)*8 + e], e in [0,8).
// ---------------------------------------------------------------------------
__global__ void egnn_pre(const float* __restrict__ h, const float* __restrict__ ew1,
                         const float* __restrict__ eb1, const float* __restrict__ ew2,
                         const float* __restrict__ cw1,
                         float* __restrict__ Ah, float* __restrict__ Bh,
                         ushort_t* __restrict__ ew2tf, ushort_t* __restrict__ cw1tf)
{
    const int b = blockIdx.x, tid = threadIdx.x;
    if (b < 256) {
        const int n = b * 4 + (tid >> 6);
        const int c = (tid & 63) * 2;
        f2 a = *(const f2*)&eb1[c];
        f2 bb = (f2){0.f, 0.f};
        const float* hrow = h + n * HD;
        #pragma unroll 4
        for (int d = 0; d < HD; ++d) {
            const float hv = hrow[d];
            const f2 w1 = *(const f2*)&ew1[d * HIDD + c];
            const f2 w2 = *(const f2*)&ew1[(HD + d) * HIDD + c];
            a += hv * w1;
            bb += hv * w2;
        }
        *(f2*)&Ah[n * HIDD + c] = a;
        *(f2*)&Bh[n * HIDD + c] = bb;
    } else if (b == 256) {
        // ew2^T frags: f = mt*8+ks (mt<2, ks<8): lane: msg = mt*32+(l&31),
        // hid = ks*16 + (l>>5)*8 + e ; value = ew2[hid][msg]
        #pragma unroll
        for (int uu = 0; uu < 4; ++uu) {
            const int fl = uu * 256 + tid;
            const int f = fl >> 6, l = fl & 63;
            const int mt = f >> 3, ks = f & 7;
            const int msg = mt * 32 + (l & 31);
            const int hidb = ks * 16 + (l >> 5) * 8;
            u32x4 pk;
            #pragma unroll
            for (int p = 0; p < 4; ++p)
                pk[p] = pack2(ew2[(hidb + 2 * p) * MSGD + msg],
                              ew2[(hidb + 2 * p + 1) * MSGD + msg]);
            *(u32x4*)&ew2tf[fl * 8] = pk;
        }
    } else {
        // cw1^T frags: f = mt*4+k (mt<4, k<4): lane: hid = mt*32+(l&31),
        // msg = k*16 + (l>>5)*8 + e ; value = cw1[msg][hid]
        #pragma unroll
        for (int uu = 0; uu < 4; ++uu) {
            const int fl = uu * 256 + tid;
            const int f = fl >> 6, l = fl & 63;
            const int mt = f >> 2, k = f & 3;
            const int hid = mt * 32 + (l & 31);
            const int msgb = k * 16 + (l >> 5) * 8;
            u32x4 pk;
            #pragma unroll
            for (int p = 0; p < 4; ++p)
                pk[p] = pack2(cw1[(msgb + 2 * p) * HIDD + hid],
                              cw1[(msgb + 2 * p + 1) * HIDD + hid]);
            *(u32x4*)&cw1tf[fl * 8] = pk;
        }
    }
}

// ---------------------------------------------------------------------------
// Kernel B: fused edge pipeline, 32x32x16 MFMA, transposed-operand form.
// WG = 4 waves; wave w owns i = blockIdx.x*4+w. jh = blockIdx.y (4 slices),
// 8 chunks of 32 j each. Per lane: j = lane&31, hi = lane>>5.
//   GEMM1: m^T = ew2^T @ s^T  (s built in B-frag layout, one j per lane)
//   exchange: single xor32 round -> m^T B-frags for GEMM2
//   GEMM2: t^T = cw1^T @ m^T ; phi = silu(t+cb1)@cw2 + cb2 (in-lane + xor32)
// ---------------------------------------------------------------------------
__global__ __launch_bounds__(256, 4) void egnn_edge(
    const float* __restrict__ x, const float* __restrict__ wr_row,
    const float* __restrict__ Ah, const float* __restrict__ Bh,
    const ushort_t* __restrict__ ew2tf, const ushort_t* __restrict__ cw1tf,
    const float* __restrict__ eb2, const float* __restrict__ cb1,
    const float* __restrict__ cw2, const float* __restrict__ cb2,
    float* __restrict__ m_part, float* __restrict__ xu_part)
{
    __shared__ ushort_t ew2t_lds[16][512];  // 16 KB
    __shared__ float    bh_lds[32][132];    // 16.9 KB (stride 132 -> conflict-free b128)
    __shared__ float    ah_lds[4][128];
    __shared__ float    wr_lds[128];
    __shared__ float    cb1_lds[128];
    __shared__ float    cw2_lds[128];
    __shared__ float    eb2_lds[64];
    __shared__ float    xj_lds[32][4];

    const int tid = threadIdx.x;
    const int w = tid >> 6, lane = tid & 63;
    const int j32 = lane & 31, hi = lane >> 5;
    const int i0 = blockIdx.x * 4, jh = blockIdx.y;
    const int i = i0 + w;

    // prologue
    {
        const u32x4* s1 = (const u32x4*)ew2tf;
        u32x4* d1 = (u32x4*)&ew2t_lds[0][0];
        #pragma unroll
        for (int uu = 0; uu < 4; ++uu) d1[uu * 256 + tid] = s1[uu * 256 + tid];
        const int r = tid >> 6, c = (tid & 63) * 2;
        *(f2*)&ah_lds[r][c] = *(const f2*)&Ah[(i0 + r) * HIDD + c];
        if (tid < 128) {
            wr_lds[tid]  = wr_row[tid];
            cb1_lds[tid] = cb1[tid];
            cw2_lds[tid] = cw2[tid];
            if (tid < 64) eb2_lds[tid] = eb2[tid];
        }
    }
    const float cb2s = cb2[0];
    const float xi0 = x[i * 3 + 0], xi1 = x[i * 3 + 1], xi2 = x[i * 3 + 2];

    f4 macc[2][4];
    #pragma unroll
    for (int mt = 0; mt < 2; ++mt)
        #pragma unroll
        for (int g = 0; g < 4; ++g) macc[mt][g] = (f4){0.f, 0.f, 0.f, 0.f};
    float xq0 = 0.f, xq1 = 0.f, xq2 = 0.f;

    for (int jc = 0; jc < 8; ++jc) {
        const int j0 = jh * 256 + jc * 32;
        __syncthreads();
        #pragma unroll
        for (int uu = 0; uu < 4; ++uu) {
            const int idx = uu * 256 + tid, row = idx >> 5, c4 = (idx & 31) * 4;
            *(f4*)&bh_lds[row][c4] = *(const f4*)&Bh[(j0 + row) * HIDD + c4];
        }
        if (tid < 128) {
            const int r = tid >> 2, c = tid & 3;
            xj_lds[r][c] = (c < 3) ? x[(j0 + r) * 3 + c] : 0.f;
        }
        __syncthreads();

        const f4 xj = *(const f4*)&xj_lds[j32][0];
        const float d0 = xi0 - xj[0], d1v = xi1 - xj[1], d2v = xi2 - xj[2];
        const float r2 = d0 * d0 + d1v * d1v + d2v * d2v;

        // ---- GEMM1: m^T = ew2^T @ s^T ----
        f32x16 accA = ZERO16, accB = ZERO16;
        #pragma unroll
        for (int ks = 0; ks < 8; ++ks) {
            const int hidb = ks * 16 + hi * 8;
            const f4 a0 = *(const f4*)&ah_lds[w][hidb];
            const f4 a1 = *(const f4*)&ah_lds[w][hidb + 4];
            const f4 w0 = *(const f4*)&wr_lds[hidb];
            const f4 w1 = *(const f4*)&wr_lds[hidb + 4];
            const f4 b0 = *(const f4*)&bh_lds[j32][hidb];
            const f4 b1 = *(const f4*)&bh_lds[j32][hidb + 4];
            bf16x8 sf;
            #pragma unroll
            for (int e = 0; e < 4; ++e) {
                sf[e]     = (__bf16)silu_f(fmaf(r2, w0[e], a0[e]) + b0[e]);
                sf[e + 4] = (__bf16)silu_f(fmaf(r2, w1[e], a1[e]) + b1[e]);
            }
            const bf16x8 af0 = *(const bf16x8*)&ew2t_lds[ks][lane * 8];
            const bf16x8 af1 = *(const bf16x8*)&ew2t_lds[8 + ks][lane * 8];
            accA = __builtin_amdgcn_mfma_f32_32x32x16_bf16(af0, sf, accA, 0, 0, 0);
            accB = __builtin_amdgcn_mfma_f32_32x32x16_bf16(af1, sf, accB, 0, 0, 0);
        }

        // bias + self-zero + macc accumulate + bf16 pack
        const bool has_self = (i >= j0) && (i < j0 + 32);
        const bool is_self = has_self && ((j0 + j32) == i);
        unsigned pk0[8], pk1[8];
        #pragma unroll
        for (int g = 0; g < 4; ++g) {
            f4 qa, qb;
            #pragma unroll
            for (int rr = 0; rr < 4; ++rr) { qa[rr] = accA[g * 4 + rr]; qb[rr] = accB[g * 4 + rr]; }
            const f4 ea = *(const f4*)&eb2_lds[8 * g + 4 * hi];
            const f4 eb = *(const f4*)&eb2_lds[32 + 8 * g + 4 * hi];
            qa += ea; qb += eb;
            #pragma unroll
            for (int rr = 0; rr < 4; ++rr) {
                qa[rr] = is_self ? 0.f : qa[rr];
                qb[rr] = is_self ? 0.f : qb[rr];
            }
            macc[0][g] += qa; macc[1][g] += qb;
            pk0[g * 2]     = pack2(qa[0], qa[1]);
            pk0[g * 2 + 1] = pack2(qa[2], qa[3]);
            pk1[g * 2]     = pack2(qb[0], qb[1]);
            pk1[g * 2 + 1] = pack2(qb[2], qb[3]);
        }

        // ---- exchange (xor32) -> GEMM2 B-frags: msg = k*16 + hi*8 + e ----
        bf16x8 mfrag[4];
        #pragma unroll
        for (int k = 0; k < 4; ++k) {
            // entry for M: pk[M>>2][(M&3)*2 + t]; M_lo = 2k (hi=0 side), M_hi = 2k+1
            unsigned lo0, lo1, hh0, hh1;
            {
                constexpr_helper:;
            }
            {
                const int M = 2 * k;
                lo0 = (M >> 2) ? pk1[(M & 3) * 2] : pk0[(M & 3) * 2];
                lo1 = (M >> 2) ? pk1[(M & 3) * 2 + 1] : pk0[(M & 3) * 2 + 1];
            }
            {
                const int M = 2 * k + 1;
                hh0 = (M >> 2) ? pk1[(M & 3) * 2] : pk0[(M & 3) * 2];
                hh1 = (M >> 2) ? pk1[(M & 3) * 2 + 1] : pk0[(M & 3) * 2 + 1];
            }
            const unsigned own0 = hi ? hh0 : lo0, own1 = hi ? hh1 : lo1;
            const unsigned snd0 = hi ? lo0 : hh0, snd1 = hi ? lo1 : hh1;
            const unsigned rcv0 = __shfl_xor(snd0, 32), rcv1 = __shfl_xor(snd1, 32);
            u32x4 fr;
            fr[0] = hi ? rcv0 : own0;  // from hi=0 lane (e 0..3)
            fr[1] = hi ? rcv1 : own1;
            fr[2] = hi ? own0 : rcv0;  // from hi=1 lane (e 4..7)
            fr[3] = hi ? own1 : rcv1;
            mfrag[k] = __builtin_bit_cast(bf16x8, fr);
        }

        // ---- GEMM2: t^T = cw1^T @ m^T ; phi ----
        float phi = 0.f;
        #pragma unroll
        for (int half = 0; half < 2; ++half) {
            f32x16 t0 = ZERO16, t1 = ZERO16;
            #pragma unroll
            for (int k = 0; k < 4; ++k) {
                const bf16x8 A0 = *(const bf16x8*)&cw1tf[(((half * 2 + 0) * 4 + k) * 64 + lane) * 8];
                const bf16x8 A1 = *(const bf16x8*)&cw1tf[(((half * 2 + 1) * 4 + k) * 64 + lane) * 8];
                t0 = __builtin_amdgcn_mfma_f32_32x32x16_bf16(A0, mfrag[k], t0, 0, 0, 0);
                t1 = __builtin_amdgcn_mfma_f32_32x32x16_bf16(A1, mfrag[k], t1, 0, 0, 0);
            }
            #pragma unroll
            for (int g = 0; g < 4; ++g) {
                const int hb0 = (half * 2 + 0) * 32 + 8 * g + 4 * hi;
                const int hb1 = (half * 2 + 1) * 32 + 8 * g + 4 * hi;
                const f4 c10 = *(const f4*)&cb1_lds[hb0];
                const f4 c20 = *(const f4*)&cw2_lds[hb0];
                const f4 c11 = *(const f4*)&cb1_lds[hb1];
                const f4 c21 = *(const f4*)&cw2_lds[hb1];
                #pragma unroll
                for (int rr = 0; rr < 4; ++rr) {
                    phi += silu_f(t0[g * 4 + rr] + c10[rr]) * c20[rr];
                    phi += silu_f(t1[g * 4 + rr] + c11[rr]) * c21[rr];
                }
            }
        }
        phi += __shfl_xor(phi, 32);
        phi = (phi + cb2s) * 0.5f;   // both halves accumulate -> 0.5x each
        xq0 += d0 * phi; xq1 += d1v * phi; xq2 += d2v * phi;
    }

    // epilogue: reduce macc over the 32 j-lanes within each half
    #pragma unroll
    for (int mask = 1; mask <= 16; mask <<= 1)
        #pragma unroll
        for (int mt = 0; mt < 2; ++mt)
            #pragma unroll
            for (int g = 0; g < 4; ++g)
                #pragma unroll
                for (int rr = 0; rr < 4; ++rr)
                    macc[mt][g][rr] += __shfl_xor(macc[mt][g][rr], mask);
    if (j32 == 0) {
        #pragma unroll
        for (int mt = 0; mt < 2; ++mt)
            #pragma unroll
            for (int g = 0; g < 4; ++g)
                *(f4*)&m_part[(jh * NN + i) * MSGD + mt * 32 + 8 * g + 4 * hi] = macc[mt][g];
    }
    #pragma unroll
    for (int mask = 1; mask <= 32; mask <<= 1) {
        xq0 += __shfl_xor(xq0, mask);
        xq1 += __shfl_xor(xq1, mask);
        xq2 += __shfl_xor(xq2, mask);
    }
    if (lane == 0) {
        float* dst = &xu_part[(jh * NN + i) * 3];
        dst[0] = xq0; dst[1] = xq1; dst[2] = xq2;
    }
}

// ---------------------------------------------------------------------------
// Kernel C: reduce 4 partial slices, node MLP (fp32), write outputs.
// ---------------------------------------------------------------------------
__global__ void egnn_node(const float* __restrict__ x, const float* __restrict__ h,
                          const float* __restrict__ nw1, const float* __restrict__ nb1,
                          const float* __restrict__ nw2, const float* __restrict__ nb2,
                          const float* __restrict__ m_part, const float* __restrict__ xu_part,
                          float* __restrict__ out)
{
    __shared__ float nin[8][132];
    __shared__ float zl[8][132];
    const int tid = threadIdx.x;
    const int r0 = blockIdx.x * 8;
    #pragma unroll
    for (int uu = 0; uu < 4; ++uu) {
        const int idx = uu * 256 + tid;
        const int row = idx >> 7, c = idx & 127;
        float v;
        if (c < 64) v = h[(r0 + row) * HD + c];
        else {
            const int cc = c - 64;
            v = m_part[(r0 + row) * MSGD + cc]
              + m_part[(NN + r0 + row) * MSGD + cc]
              + m_part[(2 * NN + r0 + row) * MSGD + cc]
              + m_part[(3 * NN + r0 + row) * MSGD + cc];
        }
        nin[row][c] = v;
    }
    __syncthreads();
    const int row = tid >> 5, cg = tid & 31;
    {
        const int c0 = cg * 4;
        f4 acc = *(const f4*)&nb1[c0];
        for (int k = 0; k < 128; ++k) {
            const float v = nin[row][k];
            const f4 wv = *(const f4*)&nw1[k * HIDD + c0];
            acc += v * wv;
        }
        #pragma unroll
        for (int e = 0; e < 4; ++e) zl[row][c0 + e] = silu_f(acc[e]);
    }
    __syncthreads();
    {
        const int c0 = cg * 2;
        f2 acc = *(const f2*)&nb2[c0];
        for (int k = 0; k < 128; ++k) {
            const float v = zl[row][k];
            const f2 wv = *(const f2*)&nw2[k * HD + c0];
            acc += v * wv;
        }
        const int n = r0 + row;
        const f2 hv = *(const f2*)&h[n * HD + c0];
        *(f2*)&out[3072 + n * HD + c0] = hv + acc;
    }
    if (tid < 24) {
        const int r = tid / 3, c = tid - 3 * r;
        const int n = r0 + r;
        const float xu = xu_part[n * 3 + c] + xu_part[(NN + n) * 3 + c]
                       + xu_part[(2 * NN + n) * 3 + c] + xu_part[(3 * NN + n) * 3 + c];
        out[n * 3 + c] = x[n * 3 + c] + xu * (1.0f / 1023.0f);
    }
}

// ---------------------------------------------------------------------------
extern "C" void kernel_launch(void* const* d_in, const int* in_sizes, int n_in,
                              void* d_out, int out_size, void* d_ws, size_t ws_size,
                              hipStream_t stream)
{
    const float* x   = (const float*)d_in[0];
    const float* h   = (const float*)d_in[1];
    const float* ew1 = (const float*)d_in[2];
    const float* eb1 = (const float*)d_in[3];
    const float* ew2 = (const float*)d_in[4];
    const float* eb2 = (const float*)d_in[5];
    const float* nw1 = (const float*)d_in[6];
    const float* nb1 = (const float*)d_in[7];
    const float* nw2 = (const float*)d_in[8];
    const float* nb2 = (const float*)d_in[9];
    const float* cw1 = (const float*)d_in[10];
    const float* cb1 = (const float*)d_in[11];
    const float* cw2 = (const float*)d_in[12];
    const float* cb2 = (const float*)d_in[13];
    float* out = (float*)d_out;

    char* ws = (char*)d_ws;
    float*    Ah      = (float*)(ws);                               // 512 KB
    float*    Bh      = (float*)(ws + (512 << 10));                 // 512 KB
    ushort_t* ew2tf   = (ushort_t*)(ws + (1024 << 10));             // 16 KB
    ushort_t* cw1tf   = (ushort_t*)(ws + (1040 << 10));             // 16 KB
    float*    m_part  = (float*)(ws + (1056 << 10));                // 1 MB
    float*    xu_part = (float*)(ws + (2080 << 10));                // 48 KB

    egnn_pre<<<dim3(258), dim3(256), 0, stream>>>(h, ew1, eb1, ew2, cw1, Ah, Bh, ew2tf, cw1tf);
    egnn_edge<<<dim3(256, 4), dim3(256), 0, stream>>>(
        x, ew1 + 128 * HIDD, Ah, Bh, ew2tf, cw1tf, eb2, cb1, cw2, cb2, m_part, xu_part);
    egnn_node<<<dim3(128), dim3(256), 0, stream>>>(x, h, nw1, nb1, nw2, nb2, m_part, xu_part, out);
}

// Round 4
// 260.026 us; speedup vs baseline: 1.2019x; 1.2019x over previous
//
#include <hip/hip_runtime.h>
#include <hip/hip_bf16.h>

#define NN   1024
#define HD   64
#define MSGD 64
#define HIDD 128

typedef __attribute__((ext_vector_type(4))) float f4;
typedef __attribute__((ext_vector_type(2))) float f2;
typedef __attribute__((ext_vector_type(8))) __bf16 bf16x8;
typedef __attribute__((ext_vector_type(16))) float f32x16;
typedef __attribute__((ext_vector_type(4))) unsigned int u32x4;
typedef unsigned short ushort_t;

__device__ __forceinline__ float silu_f(float v) {
    float e = __expf(-v);
    return v * __builtin_amdgcn_rcpf(1.0f + e);
}

__device__ __forceinline__ ushort_t to_bf16_bits(float v) {
    return __builtin_bit_cast(ushort_t, (__bf16)v);
}

__device__ __forceinline__ unsigned pack2(float a, float b) {
    return (unsigned)to_bf16_bits(a) | ((unsigned)to_bf16_bits(b) << 16);
}

#define ZERO16 {0.f,0.f,0.f,0.f,0.f,0.f,0.f,0.f,0.f,0.f,0.f,0.f,0.f,0.f,0.f,0.f}

// ---------------------------------------------------------------------------
// Kernel A: Ah = h@ew1[0:64] + eb1, Bh = h@ew1[64:128]; pack ew2^T / cw1^T
// into 32x32x16 MFMA A-fragment order (bf16).
// A-frag (32x32x16): lane l holds A[m = l&31][k = (l>>5)*8 + e], e in [0,8).
// ---------------------------------------------------------------------------
__global__ void egnn_pre(const float* __restrict__ h, const float* __restrict__ ew1,
                         const float* __restrict__ eb1, const float* __restrict__ ew2,
                         const float* __restrict__ cw1,
                         float* __restrict__ Ah, float* __restrict__ Bh,
                         ushort_t* __restrict__ ew2tf, ushort_t* __restrict__ cw1tf)
{
    const int b = blockIdx.x, tid = threadIdx.x;
    if (b < 256) {
        const int n = b * 4 + (tid >> 6);
        const int c = (tid & 63) * 2;
        f2 a = *(const f2*)&eb1[c];
        f2 bb = (f2){0.f, 0.f};
        const float* hrow = h + n * HD;
        #pragma unroll 4
        for (int d = 0; d < HD; ++d) {
            const float hv = hrow[d];
            const f2 w1 = *(const f2*)&ew1[d * HIDD + c];
            const f2 w2 = *(const f2*)&ew1[(HD + d) * HIDD + c];
            a += hv * w1;
            bb += hv * w2;
        }
        *(f2*)&Ah[n * HIDD + c] = a;
        *(f2*)&Bh[n * HIDD + c] = bb;
    } else if (b == 256) {
        // ew2^T frags: f = mt*8+ks (mt<2, ks<8): lane: msg = mt*32+(l&31),
        // hid = ks*16 + (l>>5)*8 + e ; value = ew2[hid][msg]
        #pragma unroll
        for (int uu = 0; uu < 4; ++uu) {
            const int fl = uu * 256 + tid;
            const int f = fl >> 6, l = fl & 63;
            const int mt = f >> 3, ks = f & 7;
            const int msg = mt * 32 + (l & 31);
            const int hidb = ks * 16 + (l >> 5) * 8;
            u32x4 pk;
            #pragma unroll
            for (int p = 0; p < 4; ++p)
                pk[p] = pack2(ew2[(hidb + 2 * p) * MSGD + msg],
                              ew2[(hidb + 2 * p + 1) * MSGD + msg]);
            *(u32x4*)&ew2tf[fl * 8] = pk;
        }
    } else {
        // cw1^T frags: f = mt*4+k (mt<4, k<4): lane: hid = mt*32+(l&31),
        // msg = k*16 + (l>>5)*8 + e ; value = cw1[msg][hid]
        #pragma unroll
        for (int uu = 0; uu < 4; ++uu) {
            const int fl = uu * 256 + tid;
            const int f = fl >> 6, l = fl & 63;
            const int mt = f >> 2, k = f & 3;
            const int hid = mt * 32 + (l & 31);
            const int msgb = k * 16 + (l >> 5) * 8;
            u32x4 pk;
            #pragma unroll
            for (int p = 0; p < 4; ++p)
                pk[p] = pack2(cw1[(msgb + 2 * p) * HIDD + hid],
                              cw1[(msgb + 2 * p + 1) * HIDD + hid]);
            *(u32x4*)&cw1tf[fl * 8] = pk;
        }
    }
}

// ---------------------------------------------------------------------------
// Kernel B: fused edge pipeline, 32x32x16 MFMA, transposed-operand form.
// WG = 4 waves; wave w owns i = blockIdx.x*4+w. jh = blockIdx.y (3 slices of
// {11,11,10} chunks of 32 j). Per lane: j = lane&31, hi = lane>>5.
// launch_bounds(256,3): ~170-reg budget -> no scratch spills (round-2 lesson:
// (256,4) forced 64 arch VGPRs + 850 MB of spill traffic).
// ---------------------------------------------------------------------------
__global__ __launch_bounds__(256, 3) void egnn_edge(
    const float* __restrict__ x, const float* __restrict__ wr_row,
    const float* __restrict__ Ah, const float* __restrict__ Bh,
    const ushort_t* __restrict__ ew2tf, const ushort_t* __restrict__ cw1tf,
    const float* __restrict__ eb2, const float* __restrict__ cb1,
    const float* __restrict__ cw2, const float* __restrict__ cb2,
    float* __restrict__ m_part, float* __restrict__ xu_part)
{
    __shared__ ushort_t ew2t_lds[16][512];  // 16 KB
    __shared__ float    bh_lds[32][132];    // 16.9 KB (stride 132: HW counter showed 0 conflicts)
    __shared__ float    ah_lds[4][128];
    __shared__ float    wr_lds[128];
    __shared__ float    cb1_lds[128];
    __shared__ float    cw2_lds[128];
    __shared__ float    eb2_lds[64];
    __shared__ float    xj_lds[32][4];

    const int tid = threadIdx.x;
    const int w = tid >> 6, lane = tid & 63;
    const int j32 = lane & 31, hi = lane >> 5;
    const int i0 = blockIdx.x * 4, jh = blockIdx.y;
    const int i = i0 + w;
    const int jc_begin = (jh == 0) ? 0 : (jh == 1) ? 11 : 22;
    const int jc_end   = (jh == 0) ? 11 : (jh == 1) ? 22 : 32;

    // prologue
    {
        const u32x4* s1 = (const u32x4*)ew2tf;
        u32x4* d1 = (u32x4*)&ew2t_lds[0][0];
        #pragma unroll
        for (int uu = 0; uu < 4; ++uu) d1[uu * 256 + tid] = s1[uu * 256 + tid];
        const int r = tid >> 6, c = (tid & 63) * 2;
        *(f2*)&ah_lds[r][c] = *(const f2*)&Ah[(i0 + r) * HIDD + c];
        if (tid < 128) {
            wr_lds[tid]  = wr_row[tid];
            cb1_lds[tid] = cb1[tid];
            cw2_lds[tid] = cw2[tid];
            if (tid < 64) eb2_lds[tid] = eb2[tid];
        }
    }
    const float cb2s = cb2[0];
    const float xi0 = x[i * 3 + 0], xi1 = x[i * 3 + 1], xi2 = x[i * 3 + 2];

    f4 macc[2][4];
    #pragma unroll
    for (int mt = 0; mt < 2; ++mt)
        #pragma unroll
        for (int g = 0; g < 4; ++g) macc[mt][g] = (f4){0.f, 0.f, 0.f, 0.f};
    float xq0 = 0.f, xq1 = 0.f, xq2 = 0.f;

    for (int jc = jc_begin; jc < jc_end; ++jc) {
        const int j0 = jc * 32;
        __syncthreads();
        #pragma unroll
        for (int uu = 0; uu < 4; ++uu) {
            const int idx = uu * 256 + tid, row = idx >> 5, c4 = (idx & 31) * 4;
            *(f4*)&bh_lds[row][c4] = *(const f4*)&Bh[(j0 + row) * HIDD + c4];
        }
        if (tid < 128) {
            const int r = tid >> 2, c = tid & 3;
            xj_lds[r][c] = (c < 3) ? x[(j0 + r) * 3 + c] : 0.f;
        }
        __syncthreads();

        const f4 xj = *(const f4*)&xj_lds[j32][0];
        const float d0 = xi0 - xj[0], d1v = xi1 - xj[1], d2v = xi2 - xj[2];
        const float r2 = d0 * d0 + d1v * d1v + d2v * d2v;

        // ---- GEMM1: m^T = ew2^T @ s^T ----
        f32x16 accA = ZERO16, accB = ZERO16;
        #pragma unroll
        for (int ks = 0; ks < 8; ++ks) {
            const int hidb = ks * 16 + hi * 8;
            const f4 a0 = *(const f4*)&ah_lds[w][hidb];
            const f4 a1 = *(const f4*)&ah_lds[w][hidb + 4];
            const f4 w0 = *(const f4*)&wr_lds[hidb];
            const f4 w1 = *(const f4*)&wr_lds[hidb + 4];
            const f4 b0 = *(const f4*)&bh_lds[j32][hidb];
            const f4 b1 = *(const f4*)&bh_lds[j32][hidb + 4];
            bf16x8 sf;
            #pragma unroll
            for (int e = 0; e < 4; ++e) {
                sf[e]     = (__bf16)silu_f(fmaf(r2, w0[e], a0[e]) + b0[e]);
                sf[e + 4] = (__bf16)silu_f(fmaf(r2, w1[e], a1[e]) + b1[e]);
            }
            const bf16x8 af0 = *(const bf16x8*)&ew2t_lds[ks][lane * 8];
            const bf16x8 af1 = *(const bf16x8*)&ew2t_lds[8 + ks][lane * 8];
            accA = __builtin_amdgcn_mfma_f32_32x32x16_bf16(af0, sf, accA, 0, 0, 0);
            accB = __builtin_amdgcn_mfma_f32_32x32x16_bf16(af1, sf, accB, 0, 0, 0);
        }

        // bias + self-zero + macc accumulate + bf16 pack
        const bool has_self = (i >= j0) && (i < j0 + 32);
        const bool is_self = has_self && ((j0 + j32) == i);
        unsigned pk0[8], pk1[8];
        #pragma unroll
        for (int g = 0; g < 4; ++g) {
            f4 qa, qb;
            #pragma unroll
            for (int rr = 0; rr < 4; ++rr) { qa[rr] = accA[g * 4 + rr]; qb[rr] = accB[g * 4 + rr]; }
            const f4 ea = *(const f4*)&eb2_lds[8 * g + 4 * hi];
            const f4 eb = *(const f4*)&eb2_lds[32 + 8 * g + 4 * hi];
            qa += ea; qb += eb;
            #pragma unroll
            for (int rr = 0; rr < 4; ++rr) {
                qa[rr] = is_self ? 0.f : qa[rr];
                qb[rr] = is_self ? 0.f : qb[rr];
            }
            macc[0][g] += qa; macc[1][g] += qb;
            pk0[g * 2]     = pack2(qa[0], qa[1]);
            pk0[g * 2 + 1] = pack2(qa[2], qa[3]);
            pk1[g * 2]     = pack2(qb[0], qb[1]);
            pk1[g * 2 + 1] = pack2(qb[2], qb[3]);
        }

        // ---- exchange (xor32) -> GEMM2 B-frags: msg = k*16 + hi*8 + e ----
        bf16x8 mfrag[4];
        #pragma unroll
        for (int k = 0; k < 4; ++k) {
            unsigned lo0, lo1, hh0, hh1;
            {
                const int M = 2 * k;
                lo0 = (M >> 2) ? pk1[(M & 3) * 2] : pk0[(M & 3) * 2];
                lo1 = (M >> 2) ? pk1[(M & 3) * 2 + 1] : pk0[(M & 3) * 2 + 1];
            }
            {
                const int M = 2 * k + 1;
                hh0 = (M >> 2) ? pk1[(M & 3) * 2] : pk0[(M & 3) * 2];
                hh1 = (M >> 2) ? pk1[(M & 3) * 2 + 1] : pk0[(M & 3) * 2 + 1];
            }
            const unsigned own0 = hi ? hh0 : lo0, own1 = hi ? hh1 : lo1;
            const unsigned snd0 = hi ? lo0 : hh0, snd1 = hi ? lo1 : hh1;
            const unsigned rcv0 = __shfl_xor(snd0, 32), rcv1 = __shfl_xor(snd1, 32);
            u32x4 fr;
            fr[0] = hi ? rcv0 : own0;  // from hi=0 lane (e 0..3)
            fr[1] = hi ? rcv1 : own1;
            fr[2] = hi ? own0 : rcv0;  // from hi=1 lane (e 4..7)
            fr[3] = hi ? own1 : rcv1;
            mfrag[k] = __builtin_bit_cast(bf16x8, fr);
        }

        // ---- GEMM2: t^T = cw1^T @ m^T ; phi ----
        float phi = 0.f;
        #pragma unroll
        for (int half = 0; half < 2; ++half) {
            f32x16 t0 = ZERO16, t1 = ZERO16;
            #pragma unroll
            for (int k = 0; k < 4; ++k) {
                const bf16x8 A0 = *(const bf16x8*)&cw1tf[(((half * 2 + 0) * 4 + k) * 64 + lane) * 8];
                const bf16x8 A1 = *(const bf16x8*)&cw1tf[(((half * 2 + 1) * 4 + k) * 64 + lane) * 8];
                t0 = __builtin_amdgcn_mfma_f32_32x32x16_bf16(A0, mfrag[k], t0, 0, 0, 0);
                t1 = __builtin_amdgcn_mfma_f32_32x32x16_bf16(A1, mfrag[k], t1, 0, 0, 0);
            }
            #pragma unroll
            for (int g = 0; g < 4; ++g) {
                const int hb0 = (half * 2 + 0) * 32 + 8 * g + 4 * hi;
                const int hb1 = (half * 2 + 1) * 32 + 8 * g + 4 * hi;
                const f4 c10 = *(const f4*)&cb1_lds[hb0];
                const f4 c20 = *(const f4*)&cw2_lds[hb0];
                const f4 c11 = *(const f4*)&cb1_lds[hb1];
                const f4 c21 = *(const f4*)&cw2_lds[hb1];
                #pragma unroll
                for (int rr = 0; rr < 4; ++rr) {
                    phi += silu_f(t0[g * 4 + rr] + c10[rr]) * c20[rr];
                    phi += silu_f(t1[g * 4 + rr] + c11[rr]) * c21[rr];
                }
            }
        }
        phi += __shfl_xor(phi, 32);
        phi = (phi + cb2s) * 0.5f;   // both halves accumulate -> 0.5x each
        xq0 += d0 * phi; xq1 += d1v * phi; xq2 += d2v * phi;
    }

    // epilogue: reduce macc over the 32 j-lanes within each half
    #pragma unroll
    for (int mask = 1; mask <= 16; mask <<= 1)
        #pragma unroll
        for (int mt = 0; mt < 2; ++mt)
            #pragma unroll
            for (int g = 0; g < 4; ++g)
                #pragma unroll
                for (int rr = 0; rr < 4; ++rr)
                    macc[mt][g][rr] += __shfl_xor(macc[mt][g][rr], mask);
    if (j32 == 0) {
        #pragma unroll
        for (int mt = 0; mt < 2; ++mt)
            #pragma unroll
            for (int g = 0; g < 4; ++g)
                *(f4*)&m_part[(jh * NN + i) * MSGD + mt * 32 + 8 * g + 4 * hi] = macc[mt][g];
    }
    #pragma unroll
    for (int mask = 1; mask <= 32; mask <<= 1) {
        xq0 += __shfl_xor(xq0, mask);
        xq1 += __shfl_xor(xq1, mask);
        xq2 += __shfl_xor(xq2, mask);
    }
    if (lane == 0) {
        float* dst = &xu_part[(jh * NN + i) * 3];
        dst[0] = xq0; dst[1] = xq1; dst[2] = xq2;
    }
}

// ---------------------------------------------------------------------------
// Kernel C: reduce 3 partial slices, node MLP (fp32), write outputs.
// ---------------------------------------------------------------------------
__global__ void egnn_node(const float* __restrict__ x, const float* __restrict__ h,
                          const float* __restrict__ nw1, const float* __restrict__ nb1,
                          const float* __restrict__ nw2, const float* __restrict__ nb2,
                          const float* __restrict__ m_part, const float* __restrict__ xu_part,
                          float* __restrict__ out)
{
    __shared__ float nin[8][132];
    __shared__ float zl[8][132];
    const int tid = threadIdx.x;
    const int r0 = blockIdx.x * 8;
    #pragma unroll
    for (int uu = 0; uu < 4; ++uu) {
        const int idx = uu * 256 + tid;
        const int row = idx >> 7, c = idx & 127;
        float v;
        if (c < 64) v = h[(r0 + row) * HD + c];
        else {
            const int cc = c - 64;
            v = m_part[(r0 + row) * MSGD + cc]
              + m_part[(NN + r0 + row) * MSGD + cc]
              + m_part[(2 * NN + r0 + row) * MSGD + cc];
        }
        nin[row][c] = v;
    }
    __syncthreads();
    const int row = tid >> 5, cg = tid & 31;
    {
        const int c0 = cg * 4;
        f4 acc = *(const f4*)&nb1[c0];
        for (int k = 0; k < 128; ++k) {
            const float v = nin[row][k];
            const f4 wv = *(const f4*)&nw1[k * HIDD + c0];
            acc += v * wv;
        }
        #pragma unroll
        for (int e = 0; e < 4; ++e) zl[row][c0 + e] = silu_f(acc[e]);
    }
    __syncthreads();
    {
        const int c0 = cg * 2;
        f2 acc = *(const f2*)&nb2[c0];
        for (int k = 0; k < 128; ++k) {
            const float v = zl[row][k];
            const f2 wv = *(const f2*)&nw2[k * HD + c0];
            acc += v * wv;
        }
        const int n = r0 + row;
        const f2 hv = *(const f2*)&h[n * HD + c0];
        *(f2*)&out[3072 + n * HD + c0] = hv + acc;
    }
    if (tid < 24) {
        const int r = tid / 3, c = tid - 3 * r;
        const int n = r0 + r;
        const float xu = xu_part[n * 3 + c] + xu_part[(NN + n) * 3 + c]
                       + xu_part[(2 * NN + n) * 3 + c];
        out[n * 3 + c] = x[n * 3 + c] + xu * (1.0f / 1023.0f);
    }
}

// ---------------------------------------------------------------------------
extern "C" void kernel_launch(void* const* d_in, const int* in_sizes, int n_in,
                              void* d_out, int out_size, void* d_ws, size_t ws_size,
                              hipStream_t stream)
{
    const float* x   = (const float*)d_in[0];
    const float* h   = (const float*)d_in[1];
    const float* ew1 = (const float*)d_in[2];
    const float* eb1 = (const float*)d_in[3];
    const float* ew2 = (const float*)d_in[4];
    const float* eb2 = (const float*)d_in[5];
    const float* nw1 = (const float*)d_in[6];
    const float* nb1 = (const float*)d_in[7];
    const float* nw2 = (const float*)d_in[8];
    const float* nb2 = (const float*)d_in[9];
    const float* cw1 = (const float*)d_in[10];
    const float* cb1 = (const float*)d_in[11];
    const float* cw2 = (const float*)d_in[12];
    const float* cb2 = (const float*)d_in[13];
    float* out = (float*)d_out;

    char* ws = (char*)d_ws;
    float*    Ah      = (float*)(ws);                               // 512 KB
    float*    Bh      = (float*)(ws + (512 << 10));                 // 512 KB
    ushort_t* ew2tf   = (ushort_t*)(ws + (1024 << 10));             // 16 KB
    ushort_t* cw1tf   = (ushort_t*)(ws + (1040 << 10));             // 16 KB
    float*    m_part  = (float*)(ws + (1056 << 10));                // 768 KB
    float*    xu_part = (float*)(ws + (1824 << 10));                // 36 KB

    egnn_pre<<<dim3(258), dim3(256), 0, stream>>>(h, ew1, eb1, ew2, cw1, Ah, Bh, ew2tf, cw1tf);
    egnn_edge<<<dim3(256, 3), dim3(256), 0, stream>>>(
        x, ew1 + 128 * HIDD, Ah, Bh, ew2tf, cw1tf, eb2, cb1, cw2, cb2, m_part, xu_part);
    egnn_node<<<dim3(128), dim3(256), 0, stream>>>(x, h, nw1, nb1, nw2, nb2, m_part, xu_part, out);
}

// Round 5
// 197.686 us; speedup vs baseline: 1.5809x; 1.3153x over previous
//
#include <hip/hip_runtime.h>
#include <hip/hip_bf16.h>

#define NN   1024
#define HD   64
#define MSGD 64
#define HIDD 128

typedef __attribute__((ext_vector_type(4))) float f4;
typedef __attribute__((ext_vector_type(2))) float f2;
typedef __attribute__((ext_vector_type(8))) __bf16 bf16x8;
typedef __attribute__((ext_vector_type(16))) float f32x16;
typedef __attribute__((ext_vector_type(4))) unsigned int u32x4;
typedef unsigned short ushort_t;

__device__ __forceinline__ float silu_f(float v) {
    float e = __expf(-v);
    return v * __builtin_amdgcn_rcpf(1.0f + e);
}

__device__ __forceinline__ ushort_t to_bf16_bits(float v) {
    return __builtin_bit_cast(ushort_t, (__bf16)v);
}

__device__ __forceinline__ unsigned pack2(float a, float b) {
    return (unsigned)to_bf16_bits(a) | ((unsigned)to_bf16_bits(b) << 16);
}

#define ZERO16 {0.f,0.f,0.f,0.f,0.f,0.f,0.f,0.f,0.f,0.f,0.f,0.f,0.f,0.f,0.f,0.f}

// ---------------------------------------------------------------------------
// Kernel A: Ah = h@ew1[0:64] + eb1, Bh = h@ew1[64:128]; pack ew2^T / cw1^T
// into 32x32x16 MFMA A-fragment order (bf16).
// A-frag (32x32x16): lane l holds A[m = l&31][k = (l>>5)*8 + e], e in [0,8).
// ---------------------------------------------------------------------------
__global__ void egnn_pre(const float* __restrict__ h, const float* __restrict__ ew1,
                         const float* __restrict__ eb1, const float* __restrict__ ew2,
                         const float* __restrict__ cw1,
                         float* __restrict__ Ah, float* __restrict__ Bh,
                         ushort_t* __restrict__ ew2tf, ushort_t* __restrict__ cw1tf)
{
    const int b = blockIdx.x, tid = threadIdx.x;
    if (b < 256) {
        const int n = b * 4 + (tid >> 6);
        const int c = (tid & 63) * 2;
        f2 a = *(const f2*)&eb1[c];
        f2 bb = (f2){0.f, 0.f};
        const float* hrow = h + n * HD;
        #pragma unroll 4
        for (int d = 0; d < HD; ++d) {
            const float hv = hrow[d];
            const f2 w1 = *(const f2*)&ew1[d * HIDD + c];
            const f2 w2 = *(const f2*)&ew1[(HD + d) * HIDD + c];
            a += hv * w1;
            bb += hv * w2;
        }
        *(f2*)&Ah[n * HIDD + c] = a;
        *(f2*)&Bh[n * HIDD + c] = bb;
    } else if (b == 256) {
        // ew2^T frags: f = mt*8+ks (mt<2, ks<8): lane: msg = mt*32+(l&31),
        // hid = ks*16 + (l>>5)*8 + e ; value = ew2[hid][msg]
        #pragma unroll
        for (int uu = 0; uu < 4; ++uu) {
            const int fl = uu * 256 + tid;
            const int f = fl >> 6, l = fl & 63;
            const int mt = f >> 3, ks = f & 7;
            const int msg = mt * 32 + (l & 31);
            const int hidb = ks * 16 + (l >> 5) * 8;
            u32x4 pk;
            #pragma unroll
            for (int p = 0; p < 4; ++p)
                pk[p] = pack2(ew2[(hidb + 2 * p) * MSGD + msg],
                              ew2[(hidb + 2 * p + 1) * MSGD + msg]);
            *(u32x4*)&ew2tf[fl * 8] = pk;
        }
    } else {
        // cw1^T frags: f = mt*4+k (mt<4, k<4): lane: hid = mt*32+(l&31),
        // msg = k*16 + (l>>5)*8 + e ; value = cw1[msg][hid]
        #pragma unroll
        for (int uu = 0; uu < 4; ++uu) {
            const int fl = uu * 256 + tid;
            const int f = fl >> 6, l = fl & 63;
            const int mt = f >> 2, k = f & 3;
            const int hid = mt * 32 + (l & 31);
            const int msgb = k * 16 + (l >> 5) * 8;
            u32x4 pk;
            #pragma unroll
            for (int p = 0; p < 4; ++p)
                pk[p] = pack2(cw1[(msgb + 2 * p) * HIDD + hid],
                              cw1[(msgb + 2 * p + 1) * HIDD + hid]);
            *(u32x4*)&cw1tf[fl * 8] = pk;
        }
    }
}

// ---------------------------------------------------------------------------
// Kernel B: fused edge pipeline, 32x32x16 MFMA, transposed-operand form.
// WG = 4 waves; wave w owns i = blockIdx.x*4+w. jh = blockIdx.y (2 halves of
// 16 chunks of 32 j). Per lane: j = lane&31, hi = lane>>5.
// launch_bounds(256,2): 256-reg budget -> no spills (round-2/4 lesson:
// (256,4)/(256,3) forced 64/84 arch VGPRs and 100s of MB of spill traffic).
// cw1^T frags staged in LDS (round-4 lesson: per-chunk global frag reads
// were the other big FETCH contributor).
// ---------------------------------------------------------------------------
__global__ __launch_bounds__(256, 2) void egnn_edge(
    const float* __restrict__ x, const float* __restrict__ wr_row,
    const float* __restrict__ Ah, const float* __restrict__ Bh,
    const ushort_t* __restrict__ ew2tf, const ushort_t* __restrict__ cw1tf,
    const float* __restrict__ eb2, const float* __restrict__ cb1,
    const float* __restrict__ cw2, const float* __restrict__ cb2,
    float* __restrict__ m_part, float* __restrict__ xu_part)
{
    __shared__ ushort_t ew2t_lds[16][512];  // 16 KB
    __shared__ ushort_t cw1t_lds[16][512];  // 16 KB
    __shared__ float    bh_lds[32][132];    // 16.9 KB (stride 132: 0 conflicts measured)
    __shared__ float    ah_lds[4][128];
    __shared__ float    wr_lds[128];
    __shared__ float    cb1_lds[128];
    __shared__ float    cw2_lds[128];
    __shared__ float    eb2_lds[64];
    __shared__ float    xj_lds[32][4];

    const int tid = threadIdx.x;
    const int w = tid >> 6, lane = tid & 63;
    const int j32 = lane & 31, hi = lane >> 5;
    const int i0 = blockIdx.x * 4, jh = blockIdx.y;
    const int i = i0 + w;

    // prologue: weight frags + Ah rows + small vectors into LDS
    {
        const u32x4* s1 = (const u32x4*)ew2tf;
        const u32x4* s2 = (const u32x4*)cw1tf;
        u32x4* d1 = (u32x4*)&ew2t_lds[0][0];
        u32x4* d2 = (u32x4*)&cw1t_lds[0][0];
        #pragma unroll
        for (int uu = 0; uu < 4; ++uu) {
            d1[uu * 256 + tid] = s1[uu * 256 + tid];
            d2[uu * 256 + tid] = s2[uu * 256 + tid];
        }
        const int r = tid >> 6, c = (tid & 63) * 2;
        *(f2*)&ah_lds[r][c] = *(const f2*)&Ah[(i0 + r) * HIDD + c];
        if (tid < 128) {
            wr_lds[tid]  = wr_row[tid];
            cb1_lds[tid] = cb1[tid];
            cw2_lds[tid] = cw2[tid];
            if (tid < 64) eb2_lds[tid] = eb2[tid];
        }
    }
    const float cb2s = cb2[0];
    const float xi0 = x[i * 3 + 0], xi1 = x[i * 3 + 1], xi2 = x[i * 3 + 2];

    f4 macc[2][4];
    #pragma unroll
    for (int mt = 0; mt < 2; ++mt)
        #pragma unroll
        for (int g = 0; g < 4; ++g) macc[mt][g] = (f4){0.f, 0.f, 0.f, 0.f};
    float xq0 = 0.f, xq1 = 0.f, xq2 = 0.f;

    for (int jc = 0; jc < 16; ++jc) {
        const int j0 = jh * 512 + jc * 32;
        __syncthreads();
        #pragma unroll
        for (int uu = 0; uu < 4; ++uu) {
            const int idx = uu * 256 + tid, row = idx >> 5, c4 = (idx & 31) * 4;
            *(f4*)&bh_lds[row][c4] = *(const f4*)&Bh[(j0 + row) * HIDD + c4];
        }
        if (tid < 128) {
            const int r = tid >> 2, c = tid & 3;
            xj_lds[r][c] = (c < 3) ? x[(j0 + r) * 3 + c] : 0.f;
        }
        __syncthreads();

        const f4 xj = *(const f4*)&xj_lds[j32][0];
        const float d0 = xi0 - xj[0], d1v = xi1 - xj[1], d2v = xi2 - xj[2];
        const float r2 = d0 * d0 + d1v * d1v + d2v * d2v;

        // ---- GEMM1: m^T = ew2^T @ s^T ----
        f32x16 accA = ZERO16, accB = ZERO16;
        #pragma unroll
        for (int ks = 0; ks < 8; ++ks) {
            const int hidb = ks * 16 + hi * 8;
            const f4 a0 = *(const f4*)&ah_lds[w][hidb];
            const f4 a1 = *(const f4*)&ah_lds[w][hidb + 4];
            const f4 w0 = *(const f4*)&wr_lds[hidb];
            const f4 w1 = *(const f4*)&wr_lds[hidb + 4];
            const f4 b0 = *(const f4*)&bh_lds[j32][hidb];
            const f4 b1 = *(const f4*)&bh_lds[j32][hidb + 4];
            bf16x8 sf;
            #pragma unroll
            for (int e = 0; e < 4; ++e) {
                sf[e]     = (__bf16)silu_f(fmaf(r2, w0[e], a0[e]) + b0[e]);
                sf[e + 4] = (__bf16)silu_f(fmaf(r2, w1[e], a1[e]) + b1[e]);
            }
            const bf16x8 af0 = *(const bf16x8*)&ew2t_lds[ks][lane * 8];
            const bf16x8 af1 = *(const bf16x8*)&ew2t_lds[8 + ks][lane * 8];
            accA = __builtin_amdgcn_mfma_f32_32x32x16_bf16(af0, sf, accA, 0, 0, 0);
            accB = __builtin_amdgcn_mfma_f32_32x32x16_bf16(af1, sf, accB, 0, 0, 0);
        }

        // bias + self-zero + macc accumulate + bf16 pack
        const bool has_self = (i >= j0) && (i < j0 + 32);
        const bool is_self = has_self && ((j0 + j32) == i);
        unsigned pk0[8], pk1[8];
        #pragma unroll
        for (int g = 0; g < 4; ++g) {
            f4 qa, qb;
            #pragma unroll
            for (int rr = 0; rr < 4; ++rr) { qa[rr] = accA[g * 4 + rr]; qb[rr] = accB[g * 4 + rr]; }
            const f4 ea = *(const f4*)&eb2_lds[8 * g + 4 * hi];
            const f4 eb = *(const f4*)&eb2_lds[32 + 8 * g + 4 * hi];
            qa += ea; qb += eb;
            #pragma unroll
            for (int rr = 0; rr < 4; ++rr) {
                qa[rr] = is_self ? 0.f : qa[rr];
                qb[rr] = is_self ? 0.f : qb[rr];
            }
            macc[0][g] += qa; macc[1][g] += qb;
            pk0[g * 2]     = pack2(qa[0], qa[1]);
            pk0[g * 2 + 1] = pack2(qa[2], qa[3]);
            pk1[g * 2]     = pack2(qb[0], qb[1]);
            pk1[g * 2 + 1] = pack2(qb[2], qb[3]);
        }

        // ---- exchange (xor32) -> GEMM2 B-frags: msg = k*16 + hi*8 + e ----
        bf16x8 mfrag[4];
        #pragma unroll
        for (int k = 0; k < 4; ++k) {
            unsigned lo0, lo1, hh0, hh1;
            {
                const int M = 2 * k;
                lo0 = (M >> 2) ? pk1[(M & 3) * 2] : pk0[(M & 3) * 2];
                lo1 = (M >> 2) ? pk1[(M & 3) * 2 + 1] : pk0[(M & 3) * 2 + 1];
            }
            {
                const int M = 2 * k + 1;
                hh0 = (M >> 2) ? pk1[(M & 3) * 2] : pk0[(M & 3) * 2];
                hh1 = (M >> 2) ? pk1[(M & 3) * 2 + 1] : pk0[(M & 3) * 2 + 1];
            }
            const unsigned own0 = hi ? hh0 : lo0, own1 = hi ? hh1 : lo1;
            const unsigned snd0 = hi ? lo0 : hh0, snd1 = hi ? lo1 : hh1;
            const unsigned rcv0 = __shfl_xor(snd0, 32), rcv1 = __shfl_xor(snd1, 32);
            u32x4 fr;
            fr[0] = hi ? rcv0 : own0;  // from hi=0 lane (e 0..3)
            fr[1] = hi ? rcv1 : own1;
            fr[2] = hi ? own0 : rcv0;  // from hi=1 lane (e 4..7)
            fr[3] = hi ? own1 : rcv1;
            mfrag[k] = __builtin_bit_cast(bf16x8, fr);
        }

        // ---- GEMM2: t^T = cw1^T @ m^T ; phi ----
        float phi = 0.f;
        #pragma unroll
        for (int half = 0; half < 2; ++half) {
            f32x16 t0 = ZERO16, t1 = ZERO16;
            #pragma unroll
            for (int k = 0; k < 4; ++k) {
                const bf16x8 A0 = *(const bf16x8*)&cw1t_lds[(half * 2 + 0) * 4 + k][lane * 8];
                const bf16x8 A1 = *(const bf16x8*)&cw1t_lds[(half * 2 + 1) * 4 + k][lane * 8];
                t0 = __builtin_amdgcn_mfma_f32_32x32x16_bf16(A0, mfrag[k], t0, 0, 0, 0);
                t1 = __builtin_amdgcn_mfma_f32_32x32x16_bf16(A1, mfrag[k], t1, 0, 0, 0);
            }
            #pragma unroll
            for (int g = 0; g < 4; ++g) {
                const int hb0 = (half * 2 + 0) * 32 + 8 * g + 4 * hi;
                const int hb1 = (half * 2 + 1) * 32 + 8 * g + 4 * hi;
                const f4 c10 = *(const f4*)&cb1_lds[hb0];
                const f4 c20 = *(const f4*)&cw2_lds[hb0];
                const f4 c11 = *(const f4*)&cb1_lds[hb1];
                const f4 c21 = *(const f4*)&cw2_lds[hb1];
                #pragma unroll
                for (int rr = 0; rr < 4; ++rr) {
                    phi += silu_f(t0[g * 4 + rr] + c10[rr]) * c20[rr];
                    phi += silu_f(t1[g * 4 + rr] + c11[rr]) * c21[rr];
                }
            }
        }
        phi += __shfl_xor(phi, 32);
        phi = (phi + cb2s) * 0.5f;   // both halves accumulate -> 0.5x each
        xq0 += d0 * phi; xq1 += d1v * phi; xq2 += d2v * phi;
    }

    // epilogue: reduce macc over the 32 j-lanes within each half
    #pragma unroll
    for (int mask = 1; mask <= 16; mask <<= 1)
        #pragma unroll
        for (int mt = 0; mt < 2; ++mt)
            #pragma unroll
            for (int g = 0; g < 4; ++g)
                #pragma unroll
                for (int rr = 0; rr < 4; ++rr)
                    macc[mt][g][rr] += __shfl_xor(macc[mt][g][rr], mask);
    if (j32 == 0) {
        #pragma unroll
        for (int mt = 0; mt < 2; ++mt)
            #pragma unroll
            for (int g = 0; g < 4; ++g)
                *(f4*)&m_part[(jh * NN + i) * MSGD + mt * 32 + 8 * g + 4 * hi] = macc[mt][g];
    }
    #pragma unroll
    for (int mask = 1; mask <= 32; mask <<= 1) {
        xq0 += __shfl_xor(xq0, mask);
        xq1 += __shfl_xor(xq1, mask);
        xq2 += __shfl_xor(xq2, mask);
    }
    if (lane == 0) {
        float* dst = &xu_part[(jh * NN + i) * 3];
        dst[0] = xq0; dst[1] = xq1; dst[2] = xq2;
    }
}

// ---------------------------------------------------------------------------
// Kernel C: reduce 2 partial slices, node MLP (fp32), write outputs.
// ---------------------------------------------------------------------------
__global__ void egnn_node(const float* __restrict__ x, const float* __restrict__ h,
                          const float* __restrict__ nw1, const float* __restrict__ nb1,
                          const float* __restrict__ nw2, const float* __restrict__ nb2,
                          const float* __restrict__ m_part, const float* __restrict__ xu_part,
                          float* __restrict__ out)
{
    __shared__ float nin[8][132];
    __shared__ float zl[8][132];
    const int tid = threadIdx.x;
    const int r0 = blockIdx.x * 8;
    #pragma unroll
    for (int uu = 0; uu < 4; ++uu) {
        const int idx = uu * 256 + tid;
        const int row = idx >> 7, c = idx & 127;
        float v;
        if (c < 64) v = h[(r0 + row) * HD + c];
        else {
            const int cc = c - 64;
            v = m_part[(r0 + row) * MSGD + cc]
              + m_part[(NN + r0 + row) * MSGD + cc];
        }
        nin[row][c] = v;
    }
    __syncthreads();
    const int row = tid >> 5, cg = tid & 31;
    {
        const int c0 = cg * 4;
        f4 acc = *(const f4*)&nb1[c0];
        for (int k = 0; k < 128; ++k) {
            const float v = nin[row][k];
            const f4 wv = *(const f4*)&nw1[k * HIDD + c0];
            acc += v * wv;
        }
        #pragma unroll
        for (int e = 0; e < 4; ++e) zl[row][c0 + e] = silu_f(acc[e]);
    }
    __syncthreads();
    {
        const int c0 = cg * 2;
        f2 acc = *(const f2*)&nb2[c0];
        for (int k = 0; k < 128; ++k) {
            const float v = zl[row][k];
            const f2 wv = *(const f2*)&nw2[k * HD + c0];
            acc += v * wv;
        }
        const int n = r0 + row;
        const f2 hv = *(const f2*)&h[n * HD + c0];
        *(f2*)&out[3072 + n * HD + c0] = hv + acc;
    }
    if (tid < 24) {
        const int r = tid / 3, c = tid - 3 * r;
        const int n = r0 + r;
        const float xu = xu_part[n * 3 + c] + xu_part[(NN + n) * 3 + c];
        out[n * 3 + c] = x[n * 3 + c] + xu * (1.0f / 1023.0f);
    }
}

// ---------------------------------------------------------------------------
extern "C" void kernel_launch(void* const* d_in, const int* in_sizes, int n_in,
                              void* d_out, int out_size, void* d_ws, size_t ws_size,
                              hipStream_t stream)
{
    const float* x   = (const float*)d_in[0];
    const float* h   = (const float*)d_in[1];
    const float* ew1 = (const float*)d_in[2];
    const float* eb1 = (const float*)d_in[3];
    const float* ew2 = (const float*)d_in[4];
    const float* eb2 = (const float*)d_in[5];
    const float* nw1 = (const float*)d_in[6];
    const float* nb1 = (const float*)d_in[7];
    const float* nw2 = (const float*)d_in[8];
    const float* nb2 = (const float*)d_in[9];
    const float* cw1 = (const float*)d_in[10];
    const float* cb1 = (const float*)d_in[11];
    const float* cw2 = (const float*)d_in[12];
    const float* cb2 = (const float*)d_in[13];
    float* out = (float*)d_out;

    char* ws = (char*)d_ws;
    float*    Ah      = (float*)(ws);                               // 512 KB
    float*    Bh      = (float*)(ws + (512 << 10));                 // 512 KB
    ushort_t* ew2tf   = (ushort_t*)(ws + (1024 << 10));             // 16 KB
    ushort_t* cw1tf   = (ushort_t*)(ws + (1040 << 10));             // 16 KB
    float*    m_part  = (float*)(ws + (1056 << 10));                // 512 KB
    float*    xu_part = (float*)(ws + (1568 << 10));                // 24 KB

    egnn_pre<<<dim3(258), dim3(256), 0, stream>>>(h, ew1, eb1, ew2, cw1, Ah, Bh, ew2tf, cw1tf);
    egnn_edge<<<dim3(256, 2), dim3(256), 0, stream>>>(
        x, ew1 + 128 * HIDD, Ah, Bh, ew2tf, cw1tf, eb2, cb1, cw2, cb2, m_part, xu_part);
    egnn_node<<<dim3(128), dim3(256), 0, stream>>>(x, h, nw1, nb1, nw2, nb2, m_part, xu_part, out);
}